// Round 6
// baseline (486.835 us; speedup 1.0000x reference)
//
#include <hip/hip_runtime.h>

#define B_DIM 8
#define S_LEN 4096
#define D_DIM 512
#define H_DIM 512

#define DECAY_F 0.90483743f   // exp(-0.1)
#define ALPHA_F 0.01f
#define EPS_F   1e-6f

// ---------------- GEMM: h[m][n] = sum_k x[m][k] * W[n][k] + bias[n] ----------------
// 128x128 tile, KT=16, single-buffer LDS, register prefetch (R3 structure).
// Wave = 8x8 thread grid, tr = lane>>3 (row), tc = lane&7 (col fast).
// Each thread: rows rbase+0..7, cols {c0..c0+3} and {c1..c1+3} with c1 = c0+32.
//  - C-store: lanes 0..7 share a row, 16B chunks at 16B stride -> 128B dense segments.
//  - LDS B-read: 8 distinct b128 at 16B stride -> all 32 banks once (conflict-free).
//  - LDS A-read: 8 distinct b128 at 32B stride -> 2-way (free).
// Per-element k-accumulation order identical to R2-R5 -> bit-identical h.
#define KT 16
__global__ __launch_bounds__(256, 3) void gemm_kernel(const float* __restrict__ x,
                                                      const float* __restrict__ W,
                                                      const float* __restrict__ bias,
                                                      float* __restrict__ out) {
    __shared__ float As[KT][132];
    __shared__ float Bs[KT][132];

    const int tid = threadIdx.x;
    const int waveId = tid >> 6;
    const int waveR = waveId & 1;        // row half of 128
    const int waveC = waveId >> 1;       // col half of 128
    const int lane = tid & 63;
    const int tr = lane >> 3;            // 0..7 (row index within wave)
    const int tc = lane & 7;             // 0..7 (col index, lane-fast)
    const int rbase = waveR * 64 + tr * 8;
    const int c0 = waveC * 64 + tc * 4;  // first col group
    const int c1 = c0 + 32;              // second col group
    const int bm = blockIdx.y * 128;
    const int bn = blockIdx.x * 128;

    const int lrow = tid >> 2;          // 0..63
    const int lk4  = (tid & 3) * 4;     // 0,4,8,12

    const float* xa = &x[(size_t)(bm + lrow) * D_DIM + lk4];
    const float* xb = &x[(size_t)(bm + lrow + 64) * D_DIM + lk4];
    const float* wa = &W[(size_t)(bn + lrow) * D_DIM + lk4];
    const float* wb = &W[(size_t)(bn + lrow + 64) * D_DIM + lk4];

    float acc[8][8];
#pragma unroll
    for (int i = 0; i < 8; ++i)
#pragma unroll
        for (int j = 0; j < 8; ++j) acc[i][j] = 0.f;

    // prologue: stage tile kk=0 into registers
    float4 a0 = *reinterpret_cast<const float4*>(xa);
    float4 a1 = *reinterpret_cast<const float4*>(xb);
    float4 b0 = *reinterpret_cast<const float4*>(wa);
    float4 b1 = *reinterpret_cast<const float4*>(wb);

    for (int kk = 0; kk < D_DIM; kk += KT) {
        __syncthreads();
        As[lk4 + 0][lrow]      = a0.x;
        As[lk4 + 1][lrow]      = a0.y;
        As[lk4 + 2][lrow]      = a0.z;
        As[lk4 + 3][lrow]      = a0.w;
        As[lk4 + 0][lrow + 64] = a1.x;
        As[lk4 + 1][lrow + 64] = a1.y;
        As[lk4 + 2][lrow + 64] = a1.z;
        As[lk4 + 3][lrow + 64] = a1.w;
        Bs[lk4 + 0][lrow]      = b0.x;
        Bs[lk4 + 1][lrow]      = b0.y;
        Bs[lk4 + 2][lrow]      = b0.z;
        Bs[lk4 + 3][lrow]      = b0.w;
        Bs[lk4 + 0][lrow + 64] = b1.x;
        Bs[lk4 + 1][lrow + 64] = b1.y;
        Bs[lk4 + 2][lrow + 64] = b1.z;
        Bs[lk4 + 3][lrow + 64] = b1.w;
        __syncthreads();

        // issue next tile's loads; latency hides under the FMA loop below
        if (kk + KT < D_DIM) {
            a0 = *reinterpret_cast<const float4*>(xa + kk + KT);
            a1 = *reinterpret_cast<const float4*>(xb + kk + KT);
            b0 = *reinterpret_cast<const float4*>(wa + kk + KT);
            b1 = *reinterpret_cast<const float4*>(wb + kk + KT);
        }

#pragma unroll
        for (int k = 0; k < KT; ++k) {
            const float4 av0 = *reinterpret_cast<const float4*>(&As[k][rbase]);
            const float4 av1 = *reinterpret_cast<const float4*>(&As[k][rbase + 4]);
            const float4 bv0 = *reinterpret_cast<const float4*>(&Bs[k][c0]);
            const float4 bv1 = *reinterpret_cast<const float4*>(&Bs[k][c1]);
            const float am[8]  = {av0.x, av0.y, av0.z, av0.w, av1.x, av1.y, av1.z, av1.w};
            const float bn_[8] = {bv0.x, bv0.y, bv0.z, bv0.w, bv1.x, bv1.y, bv1.z, bv1.w};
#pragma unroll
            for (int i = 0; i < 8; ++i)
#pragma unroll
                for (int j = 0; j < 8; ++j) acc[i][j] += am[i] * bn_[j];
        }
    }

    const float4 bias0 = *reinterpret_cast<const float4*>(&bias[bn + c0]);
    const float4 bias1 = *reinterpret_cast<const float4*>(&bias[bn + c1]);
    const float bb[8] = {bias0.x, bias0.y, bias0.z, bias0.w, bias1.x, bias1.y, bias1.z, bias1.w};

#pragma unroll
    for (int i = 0; i < 8; ++i) {
        const size_t row = (size_t)(bm + rbase + i);
        float4 o0, o1;
        o0.x = acc[i][0] + bb[0]; o0.y = acc[i][1] + bb[1];
        o0.z = acc[i][2] + bb[2]; o0.w = acc[i][3] + bb[3];
        o1.x = acc[i][4] + bb[4]; o1.y = acc[i][5] + bb[5];
        o1.z = acc[i][6] + bb[6]; o1.w = acc[i][7] + bb[7];
        *reinterpret_cast<float4*>(&out[row * H_DIM + bn + c0]) = o0;
        *reinterpret_cast<float4*>(&out[row * H_DIM + bn + c1]) = o1;
    }
}

// ---------------- Scan ---------------- (unchanged from R5)
// LDS staging via global_load_lds, double-buffered [2][32][64], counted vmcnt.
// 8-deep register read-ring, v_med3 clamps, reciprocal refinement hoisted.

__device__ __forceinline__ void stage_chunk(const float* __restrict__ gio, float* dstbase,
                                            int c, int lane) {
    const float* src = gio + (size_t)(c * 32 + (lane >> 4)) * H_DIM + ((lane & 15) << 2);
#pragma unroll
    for (int i = 0; i < 8; ++i) {
        __builtin_amdgcn_global_load_lds(
            (const __attribute__((address_space(1))) void*)(src + (size_t)i * 4 * H_DIM),
            (__attribute__((address_space(3))) void*)(dstbase + i * 256),
            16, 0, 0);
    }
}

__global__ __launch_bounds__(64, 1) void scan_kernel(float* __restrict__ io,
                                                     float* __restrict__ vout,
                                                     float* __restrict__ thout) {
    __shared__ float sbuf[2][32][64];

    const int lane = threadIdx.x;
    const int bi = blockIdx.x;        // 0..63
    const int b = bi >> 3;            // 0..7
    const int h0 = (bi & 7) << 6;     // 0,64,...,448

    float* gio = io + (size_t)b * S_LEN * H_DIM + h0;

    float v = 0.f;
    float theta = 1.f;
    float tden = theta + EPS_F;
    float rseed = __builtin_amdgcn_rcpf(tden);
    float eseed = fmaf(-tden, rseed, 1.0f);
    float r0 = fmaf(eseed, rseed, rseed);
    float cl = 32.f * theta;
    const float kZero = 0.0f;
    const float kSixteen = 16.0f;

    stage_chunk(gio, &sbuf[0][0][0], 0, lane);
    asm volatile("s_waitcnt vmcnt(0)" ::: "memory");

    const int NCHUNK = S_LEN / 32;    // 128
    for (int c = 0; c < NCHUNK; ++c) {
        if (c + 1 < NCHUNK) {
            stage_chunk(gio, &sbuf[(c + 1) & 1][0][0], c + 1, lane);
            // outstanding: stage(c)=8, stores(c-1)=32, stage(c+1)=8 -> retire oldest 8.
            asm volatile("s_waitcnt vmcnt(40)" ::: "memory");
        } else {
            asm volatile("s_waitcnt vmcnt(32)" ::: "memory");
        }
        __builtin_amdgcn_sched_barrier(0);

        const float* sb = &sbuf[c & 1][0][lane];
        float* gout = gio + (size_t)c * 32 * H_DIM + lane;

        float rb[8];
#pragma unroll
        for (int i = 0; i < 8; ++i) rb[i] = sb[i * 64];

#pragma unroll
        for (int u = 0; u < 32; ++u) {
            const float it = rb[u & 7];
            if (u + 8 < 32) rb[u & 7] = sb[(u + 8) * 64];   // issue ds_read ~8 steps early

            v = v * DECAY_F + it;
            // v = clamp(v, -cl, cl), bit-exact (cl = 32*theta >= 0, v never NaN)
            asm("v_med3_f32 %0, %1, -%2, %2" : "=v"(v) : "v"(v), "v"(cl));

            // nv = v / tden, bit-identical IEEE div (Newton-Markstein, normals only):
            const float q0 = v * r0;
            const float e1 = fmaf(-tden, q0, v);
            const float q1 = fmaf(e1, r0, q0);
            const float e2 = fmaf(-tden, q1, v);
            const float nv = fmaf(e2, r0, q1);

            float spike = floorf(nv);
            // spike = clamp(spike, 0, 16), bit-exact
            asm("v_med3_f32 %0, %1, %2, %3" : "=v"(spike) : "v"(spike), "v"(kZero), "v"(kSixteen));

            v = v - spike * theta;
            theta = theta + ALPHA_F * spike - ALPHA_F * (theta - 1.0f);

            // off-critical-path: next step's denominator, reciprocal, clamp bound
            tden = theta + EPS_F;
            const float rr = __builtin_amdgcn_rcpf(tden);
            const float ee = fmaf(-tden, rr, 1.0f);
            r0 = fmaf(ee, rr, rr);
            cl = 32.f * theta;

            gout[(size_t)u * H_DIM] = spike;
            __builtin_amdgcn_sched_barrier(0);
        }
    }

    const int chain = b * H_DIM + h0 + lane;
    vout[chain]  = v;
    thout[chain] = theta;
}

extern "C" void kernel_launch(void* const* d_in, const int* in_sizes, int n_in,
                              void* d_out, int out_size, void* d_ws, size_t ws_size,
                              hipStream_t stream) {
    const float* x    = (const float*)d_in[0];
    const float* W    = (const float*)d_in[1];
    const float* bias = (const float*)d_in[2];

    float* out   = (float*)d_out;
    float* vout  = out + (size_t)B_DIM * S_LEN * H_DIM;
    float* thout = vout + B_DIM * H_DIM;

    dim3 grid(H_DIM / 128, (B_DIM * S_LEN) / 128);
    gemm_kernel<<<grid, 256, 0, stream>>>(x, W, bias, out);

    scan_kernel<<<64, 64, 0, stream>>>(out, vout, thout);
}

// Round 7
// 393.418 us; speedup vs baseline: 1.2374x; 1.2374x over previous
//
#include <hip/hip_runtime.h>

#define B_DIM 8
#define S_LEN 4096
#define D_DIM 512
#define H_DIM 512

#define DECAY_F 0.90483743f   // exp(-0.1)
#define ALPHA_F 0.01f
#define EPS_F   1e-6f

// ---------------- GEMM: h[m][n] = sum_k x[m][k] * W[n][k] + bias[n] ----------------
// 128x128 tile, KT=16, single-buffer LDS, register prefetch.
// Wave = 8x8 grid, tr=lane>>3 (row), tc=lane&7 (col fast); cols {c0,c0+32}.
//  - C-store: lanes 0..7 dense 128B segments (R6).
//  - LDS B-read conflict-free, A-read 2-way (free).
// NO min-waves bound: the (256,3) bound in R5/R6 squeezed VGPRs to 84, which made the
// compiler fragment the epilogue stores -> 7x WRITE amplification (463MB vs 67MB in R4).
// Per-element k-accumulation order identical to R2-R6 -> bit-identical h.
#define KT 16
__global__ __launch_bounds__(256) void gemm_kernel(const float* __restrict__ x,
                                                   const float* __restrict__ W,
                                                   const float* __restrict__ bias,
                                                   float* __restrict__ out) {
    __shared__ float As[KT][132];
    __shared__ float Bs[KT][132];

    const int tid = threadIdx.x;
    const int waveId = tid >> 6;
    const int waveR = waveId & 1;        // row half of 128
    const int waveC = waveId >> 1;       // col half of 128
    const int lane = tid & 63;
    const int tr = lane >> 3;            // 0..7 (row index within wave)
    const int tc = lane & 7;             // 0..7 (col index, lane-fast)
    const int rbase = waveR * 64 + tr * 8;
    const int c0 = waveC * 64 + tc * 4;  // first col group
    const int c1 = c0 + 32;              // second col group
    const int bm = blockIdx.y * 128;
    const int bn = blockIdx.x * 128;

    const int lrow = tid >> 2;          // 0..63
    const int lk4  = (tid & 3) * 4;     // 0,4,8,12

    const float* xa = &x[(size_t)(bm + lrow) * D_DIM + lk4];
    const float* xb = &x[(size_t)(bm + lrow + 64) * D_DIM + lk4];
    const float* wa = &W[(size_t)(bn + lrow) * D_DIM + lk4];
    const float* wb = &W[(size_t)(bn + lrow + 64) * D_DIM + lk4];

    float acc[8][8];
#pragma unroll
    for (int i = 0; i < 8; ++i)
#pragma unroll
        for (int j = 0; j < 8; ++j) acc[i][j] = 0.f;

    // prologue: stage tile kk=0 into registers
    float4 a0 = *reinterpret_cast<const float4*>(xa);
    float4 a1 = *reinterpret_cast<const float4*>(xb);
    float4 b0 = *reinterpret_cast<const float4*>(wa);
    float4 b1 = *reinterpret_cast<const float4*>(wb);

    for (int kk = 0; kk < D_DIM; kk += KT) {
        __syncthreads();
        As[lk4 + 0][lrow]      = a0.x;
        As[lk4 + 1][lrow]      = a0.y;
        As[lk4 + 2][lrow]      = a0.z;
        As[lk4 + 3][lrow]      = a0.w;
        As[lk4 + 0][lrow + 64] = a1.x;
        As[lk4 + 1][lrow + 64] = a1.y;
        As[lk4 + 2][lrow + 64] = a1.z;
        As[lk4 + 3][lrow + 64] = a1.w;
        Bs[lk4 + 0][lrow]      = b0.x;
        Bs[lk4 + 1][lrow]      = b0.y;
        Bs[lk4 + 2][lrow]      = b0.z;
        Bs[lk4 + 3][lrow]      = b0.w;
        Bs[lk4 + 0][lrow + 64] = b1.x;
        Bs[lk4 + 1][lrow + 64] = b1.y;
        Bs[lk4 + 2][lrow + 64] = b1.z;
        Bs[lk4 + 3][lrow + 64] = b1.w;
        __syncthreads();

        // issue next tile's loads; latency hides under the FMA loop below
        if (kk + KT < D_DIM) {
            a0 = *reinterpret_cast<const float4*>(xa + kk + KT);
            a1 = *reinterpret_cast<const float4*>(xb + kk + KT);
            b0 = *reinterpret_cast<const float4*>(wa + kk + KT);
            b1 = *reinterpret_cast<const float4*>(wb + kk + KT);
        }

#pragma unroll
        for (int k = 0; k < KT; ++k) {
            const float4 av0 = *reinterpret_cast<const float4*>(&As[k][rbase]);
            const float4 av1 = *reinterpret_cast<const float4*>(&As[k][rbase + 4]);
            const float4 bv0 = *reinterpret_cast<const float4*>(&Bs[k][c0]);
            const float4 bv1 = *reinterpret_cast<const float4*>(&Bs[k][c1]);
            const float am[8]  = {av0.x, av0.y, av0.z, av0.w, av1.x, av1.y, av1.z, av1.w};
            const float bn_[8] = {bv0.x, bv0.y, bv0.z, bv0.w, bv1.x, bv1.y, bv1.z, bv1.w};
#pragma unroll
            for (int i = 0; i < 8; ++i)
#pragma unroll
                for (int j = 0; j < 8; ++j) acc[i][j] += am[i] * bn_[j];
        }
    }

    const float4 bias0 = *reinterpret_cast<const float4*>(&bias[bn + c0]);
    const float4 bias1 = *reinterpret_cast<const float4*>(&bias[bn + c1]);
    const float bb[8] = {bias0.x, bias0.y, bias0.z, bias0.w, bias1.x, bias1.y, bias1.z, bias1.w};

#pragma unroll
    for (int i = 0; i < 8; ++i) {
        const size_t row = (size_t)(bm + rbase + i);
        float4 o0, o1;
        o0.x = acc[i][0] + bb[0]; o0.y = acc[i][1] + bb[1];
        o0.z = acc[i][2] + bb[2]; o0.w = acc[i][3] + bb[3];
        o1.x = acc[i][4] + bb[4]; o1.y = acc[i][5] + bb[5];
        o1.z = acc[i][6] + bb[6]; o1.w = acc[i][7] + bb[7];
        *reinterpret_cast<float4*>(&out[row * H_DIM + bn + c0]) = o0;
        *reinterpret_cast<float4*>(&out[row * H_DIM + bn + c1]) = o1;
    }
}

// ---------------- Scan ----------------
// LDS staging via global_load_lds, double-buffered [2][32][64], counted vmcnt.
// 8-deep register read-ring, v_med3 clamps, reciprocal refinement hoisted.
// R7: per-step sched_barrier removed (only per-chunk fences remain) - lets the
// compiler schedule ds_reads/stores out of the ~40cy/step dependent chain.

__device__ __forceinline__ void stage_chunk(const float* __restrict__ gio, float* dstbase,
                                            int c, int lane) {
    const float* src = gio + (size_t)(c * 32 + (lane >> 4)) * H_DIM + ((lane & 15) << 2);
#pragma unroll
    for (int i = 0; i < 8; ++i) {
        __builtin_amdgcn_global_load_lds(
            (const __attribute__((address_space(1))) void*)(src + (size_t)i * 4 * H_DIM),
            (__attribute__((address_space(3))) void*)(dstbase + i * 256),
            16, 0, 0);
    }
}

__global__ __launch_bounds__(64, 1) void scan_kernel(float* __restrict__ io,
                                                     float* __restrict__ vout,
                                                     float* __restrict__ thout) {
    __shared__ float sbuf[2][32][64];

    const int lane = threadIdx.x;
    const int bi = blockIdx.x;        // 0..63
    const int b = bi >> 3;            // 0..7
    const int h0 = (bi & 7) << 6;     // 0,64,...,448

    float* gio = io + (size_t)b * S_LEN * H_DIM + h0;

    float v = 0.f;
    float theta = 1.f;
    float tden = theta + EPS_F;
    float rseed = __builtin_amdgcn_rcpf(tden);
    float eseed = fmaf(-tden, rseed, 1.0f);
    float r0 = fmaf(eseed, rseed, rseed);
    float cl = 32.f * theta;
    const float kZero = 0.0f;
    const float kSixteen = 16.0f;

    stage_chunk(gio, &sbuf[0][0][0], 0, lane);
    asm volatile("s_waitcnt vmcnt(0)" ::: "memory");

    const int NCHUNK = S_LEN / 32;    // 128
    for (int c = 0; c < NCHUNK; ++c) {
        if (c + 1 < NCHUNK) {
            stage_chunk(gio, &sbuf[(c + 1) & 1][0][0], c + 1, lane);
            // outstanding: stage(c)=8, stores(c-1)=32, stage(c+1)=8 -> retire oldest 8.
            asm volatile("s_waitcnt vmcnt(40)" ::: "memory");
        } else {
            asm volatile("s_waitcnt vmcnt(32)" ::: "memory");
        }
        __builtin_amdgcn_sched_barrier(0);

        const float* sb = &sbuf[c & 1][0][lane];
        float* gout = gio + (size_t)c * 32 * H_DIM + lane;

        float rb[8];
#pragma unroll
        for (int i = 0; i < 8; ++i) rb[i] = sb[i * 64];

#pragma unroll
        for (int u = 0; u < 32; ++u) {
            const float it = rb[u & 7];
            if (u + 8 < 32) rb[u & 7] = sb[(u + 8) * 64];   // issue ds_read ~8 steps early

            v = v * DECAY_F + it;
            // v = clamp(v, -cl, cl), bit-exact (cl = 32*theta >= 0, v never NaN)
            asm("v_med3_f32 %0, %1, -%2, %2" : "=v"(v) : "v"(v), "v"(cl));

            // nv = v / tden, bit-identical IEEE div (Newton-Markstein, normals only):
            const float q0 = v * r0;
            const float e1 = fmaf(-tden, q0, v);
            const float q1 = fmaf(e1, r0, q0);
            const float e2 = fmaf(-tden, q1, v);
            const float nv = fmaf(e2, r0, q1);

            float spike = floorf(nv);
            // spike = clamp(spike, 0, 16), bit-exact
            asm("v_med3_f32 %0, %1, %2, %3" : "=v"(spike) : "v"(spike), "v"(kZero), "v"(kSixteen));

            v = v - spike * theta;
            theta = theta + ALPHA_F * spike - ALPHA_F * (theta - 1.0f);

            // off-critical-path: next step's denominator, reciprocal, clamp bound
            tden = theta + EPS_F;
            const float rr = __builtin_amdgcn_rcpf(tden);
            const float ee = fmaf(-tden, rr, 1.0f);
            r0 = fmaf(ee, rr, rr);
            cl = 32.f * theta;

            gout[(size_t)u * H_DIM] = spike;
        }
        __builtin_amdgcn_sched_barrier(0);
    }

    const int chain = b * H_DIM + h0 + lane;
    vout[chain]  = v;
    thout[chain] = theta;
}

extern "C" void kernel_launch(void* const* d_in, const int* in_sizes, int n_in,
                              void* d_out, int out_size, void* d_ws, size_t ws_size,
                              hipStream_t stream) {
    const float* x    = (const float*)d_in[0];
    const float* W    = (const float*)d_in[1];
    const float* bias = (const float*)d_in[2];

    float* out   = (float*)d_out;
    float* vout  = out + (size_t)B_DIM * S_LEN * H_DIM;
    float* thout = vout + B_DIM * H_DIM;

    dim3 grid(H_DIM / 128, (B_DIM * S_LEN) / 128);
    gemm_kernel<<<grid, 256, 0, stream>>>(x, W, bias, out);

    scan_kernel<<<64, 64, 0, stream>>>(out, vout, thout);
}